// Round 1
// baseline (394.992 us; speedup 1.0000x reference)
//
#include <hip/hip_runtime.h>

// loss = sum_{b,i,j} exp(-(g0^2/(2*s0^2) + g1^2/(2*s1^2))) * (z2[i]+z2[j]-2*zi.zj) / (B*T^2)
// Memory-bound on gt_dT (256 MB). Gram via bf16 MFMA per 64x64 tile.

#define T_DIM 2048
#define D_DIM 128
#define B_DIM 8
#define TILE 64
#define NTHREADS 256
#define LDS_STRIDE 136   // 128 bf16 + 8 pad -> 272B rows, 16B-aligned, bank-conflict-free reads

typedef short s16x8 __attribute__((ext_vector_type(8)));
typedef float f32x4 __attribute__((ext_vector_type(4)));

__device__ __forceinline__ unsigned short f2bf(float x) {
    unsigned int u = __float_as_uint(x);
    u += 0x7fffu + ((u >> 16) & 1u);   // round-to-nearest-even
    return (unsigned short)(u >> 16);
}

__global__ void patch_loss_zero(float* out) { out[0] = 0.0f; }

__global__ __launch_bounds__(NTHREADS)
void patch_loss_kernel(const float* __restrict__ z,
                       const float* __restrict__ gt,
                       const float* __restrict__ sigma,
                       float* __restrict__ out) {
    __shared__ unsigned short zi[TILE][LDS_STRIDE];
    __shared__ unsigned short zj[TILE][LDS_STRIDE];
    __shared__ float s_tile[TILE][TILE];
    __shared__ float z2i[TILE];
    __shared__ float z2j[TILE];
    __shared__ float red[4];

    const int tid = threadIdx.x;
    const int b  = blockIdx.z;
    const int i0 = blockIdx.y * TILE;
    const int j0 = blockIdx.x * TILE;

    const float s0 = sigma[0], s1 = sigma[1];
    const float a0 = 0.5f / (s0 * s0);
    const float a1 = 0.5f / (s1 * s1);

    // ---- Phase 1: load z tiles fp32->bf16 LDS, compute row squared norms (fp32) ----
    const float4* zrow_i = (const float4*)(z + (size_t)(b * T_DIM + i0) * D_DIM);
    const float4* zrow_j = (const float4*)(z + (size_t)(b * T_DIM + j0) * D_DIM);
    #pragma unroll
    for (int k = 0; k < 8; ++k) {            // 64 rows * 32 float4 = 2048 = 8 * 256
        const int idx = tid + k * NTHREADS;
        const int row = idx >> 5;
        const int c4  = idx & 31;
        float4 vi = zrow_i[row * 32 + c4];
        float4 vj = zrow_j[row * 32 + c4];
        ushort4 pi, pj;
        pi.x = f2bf(vi.x); pi.y = f2bf(vi.y); pi.z = f2bf(vi.z); pi.w = f2bf(vi.w);
        pj.x = f2bf(vj.x); pj.y = f2bf(vj.y); pj.z = f2bf(vj.z); pj.w = f2bf(vj.w);
        *(ushort4*)&zi[row][c4 * 4] = pi;
        *(ushort4*)&zj[row][c4 * 4] = pj;
        float si = vi.x*vi.x + vi.y*vi.y + vi.z*vi.z + vi.w*vi.w;
        float sj = vj.x*vj.x + vj.y*vj.y + vj.z*vj.z + vj.w*vj.w;
        #pragma unroll
        for (int m = 16; m >= 1; m >>= 1) {  // reduce across the 32 lanes sharing this row
            si += __shfl_xor(si, m);
            sj += __shfl_xor(sj, m);
        }
        if ((tid & 31) == 0) { z2i[row] = si; z2j[row] = sj; }
    }
    __syncthreads();

    // ---- Phase 2: S = Zi * Zj^T via mfma_f32_16x16x32_bf16 ----
    const int wave = tid >> 6;
    const int lane = tid & 63;
    const int lrow = lane & 15;          // A row / B col within fragment
    const int lk   = lane >> 4;          // k-group 0..3
    const int m_base = wave * 16;        // each wave owns 16 output rows

    f32x4 acc0 = {0.f,0.f,0.f,0.f}, acc1 = {0.f,0.f,0.f,0.f};
    f32x4 acc2 = {0.f,0.f,0.f,0.f}, acc3 = {0.f,0.f,0.f,0.f};
    #pragma unroll
    for (int kk = 0; kk < 4; ++kk) {     // K = 128 = 4 * 32
        const int co = kk * 32 + lk * 8;
        s16x8 a  = *(const s16x8*)&zi[m_base + lrow][co];
        s16x8 b0 = *(const s16x8*)&zj[ 0 + lrow][co];
        s16x8 b1 = *(const s16x8*)&zj[16 + lrow][co];
        s16x8 b2 = *(const s16x8*)&zj[32 + lrow][co];
        s16x8 b3 = *(const s16x8*)&zj[48 + lrow][co];
        acc0 = __builtin_amdgcn_mfma_f32_16x16x32_bf16(a, b0, acc0, 0, 0, 0);
        acc1 = __builtin_amdgcn_mfma_f32_16x16x32_bf16(a, b1, acc1, 0, 0, 0);
        acc2 = __builtin_amdgcn_mfma_f32_16x16x32_bf16(a, b2, acc2, 0, 0, 0);
        acc3 = __builtin_amdgcn_mfma_f32_16x16x32_bf16(a, b3, acc3, 0, 0, 0);
    }
    // C/D layout: col = lane&15, row = (lane>>4)*4 + reg  [m89-verified]
    #pragma unroll
    for (int r = 0; r < 4; ++r) {
        const int row = m_base + lk * 4 + r;
        s_tile[row][ 0 + lrow] = acc0[r];
        s_tile[row][16 + lrow] = acc1[r];
        s_tile[row][32 + lrow] = acc2[r];
        s_tile[row][48 + lrow] = acc3[r];
    }
    __syncthreads();

    // ---- Phase 3: stream gt tile, accumulate w * dist^2 ----
    const int jq = tid & 31;             // float4 index -> j pair (2jq, 2jq+1)
    const int ir = tid >> 5;             // 0..7
    float facc = 0.f;
    #pragma unroll
    for (int it = 0; it < 8; ++it) {
        const int i = ir + it * 8;
        const float4* gp = (const float4*)gt
            + (((size_t)(b * T_DIM + i0 + i) * T_DIM + j0) >> 1) + jq;
        float4 g = *gp;
        const float t0 = g.x*g.x*a0 + g.y*g.y*a1;
        const float t1 = g.z*g.z*a0 + g.w*g.w*a1;
        const float w0 = __expf(-t0);
        const float w1 = __expf(-t1);
        const int jj = jq * 2;
        const float zz = z2i[i];
        const float d0 = zz + z2j[jj]     - 2.f * s_tile[i][jj];
        const float d1 = zz + z2j[jj + 1] - 2.f * s_tile[i][jj + 1];
        facc += w0 * d0 + w1 * d1;
    }

    // ---- Phase 4: block reduce + global atomic ----
    #pragma unroll
    for (int m = 32; m >= 1; m >>= 1) facc += __shfl_xor(facc, m);
    if (lane == 0) red[wave] = facc;
    __syncthreads();
    if (tid == 0) {
        const float scale = 1.0f / ((float)B_DIM * (float)T_DIM * (float)T_DIM);
        atomicAdd(out, (red[0] + red[1] + red[2] + red[3]) * scale);
    }
}

extern "C" void kernel_launch(void* const* d_in, const int* in_sizes, int n_in,
                              void* d_out, int out_size, void* d_ws, size_t ws_size,
                              hipStream_t stream) {
    const float* z     = (const float*)d_in[0];
    const float* gt    = (const float*)d_in[1];
    const float* sigma = (const float*)d_in[2];
    float* out = (float*)d_out;

    patch_loss_zero<<<1, 1, 0, stream>>>(out);
    dim3 grid(T_DIM / TILE, T_DIM / TILE, B_DIM);
    patch_loss_kernel<<<grid, NTHREADS, 0, stream>>>(z, gt, sigma, out);
}